// Round 10
// baseline (354.567 us; speedup 1.0000x reference)
//
#include <hip/hip_runtime.h>
#include <cstdint>
#include <cstddef>

typedef unsigned short u16;
typedef unsigned int   u32;
typedef unsigned short u16x4 __attribute__((ext_vector_type(4)));
typedef unsigned short u16x8 __attribute__((ext_vector_type(8)));
typedef unsigned int   u32x2 __attribute__((ext_vector_type(2)));
typedef __bf16 bf16x8 __attribute__((ext_vector_type(8)));
typedef float f32x4 __attribute__((ext_vector_type(4)));

#define MFMA16(a, b, c) __builtin_amdgcn_mfma_f32_16x16x32_bf16((a), (b), (c), 0, 0, 0)

__device__ __forceinline__ float bf2f(u16 h) {
  union { unsigned u; float f; } v; v.u = ((unsigned)h) << 16; return v.f;
}
__device__ __forceinline__ u16 f2bf(float f) {
  union { float f; unsigned u; } v; v.f = f;
  unsigned r = v.u + 0x7fffu + ((v.u >> 16) & 1u);
  return (u16)(r >> 16);
}
__device__ __forceinline__ void gll16(const u16* g, u16* l) {
  __builtin_amdgcn_global_load_lds(
      (const __attribute__((address_space(1))) void*)g,
      (__attribute__((address_space(3))) void*)l, 16, 0, 0);
}
__device__ __forceinline__ float fast_exp2(float x) {
#if __has_builtin(__builtin_amdgcn_exp2f)
  return __builtin_amdgcn_exp2f(x);
#else
  return exp2f(x);
#endif
}

// ---------------------------------------------------------------------------
// Fused prologue: one dispatch replaces prep_small + cvt_x + transpose_qkv +
// transpose_w. Block-id ranges:
//   [0,28)        prep_small   [28,4124)  cvt_x
//   [4124,7196)   transpose_qkv (Wq pre-scaled by 0.125*log2e)
//   [7196,16412)  transpose_w
// ---------------------------------------------------------------------------
__global__ __launch_bounds__(256) void prep_all(
    const float* __restrict__ bq, const float* __restrict__ bk,
    const float* __restrict__ bv, const int* __restrict__ mask,
    float* __restrict__ biasq, float* __restrict__ madd2,
    const float* __restrict__ x, u16* __restrict__ xb,
    const float* __restrict__ Wq, const float* __restrict__ Wk,
    const float* __restrict__ Wv, u16* __restrict__ Wqkv_t,
    const float* __restrict__ Wo, const float* __restrict__ W1,
    const float* __restrict__ W2, u16* __restrict__ Wo_t,
    u16* __restrict__ W1_t, u16* __restrict__ W2_t) {
  __shared__ u16 tile[32][33];
  const int id = blockIdx.x;
  const int tid = threadIdx.x;

  if (id < 28) {
    int i = id * 256 + tid;
    if (i < 3072) {
      biasq[i] = (i < 1024) ? bq[i] * 0.18033688f
                            : (i < 2048 ? bk[i - 1024] : bv[i - 2048]);
    } else if (i < 7168) {
      int j = i - 3072;
      madd2[j] = mask[j] ? -23.083120f : -1.442695e9f;  // (-16|-1e9)*log2e
    }
    return;
  }
  if (id < 4124) {
    int i = ((id - 28) * 256 + tid) * 4;
    const float4 v = *(const float4*)&x[i];
    u16x4 o;
    o[0] = f2bf(v.x); o[1] = f2bf(v.y); o[2] = f2bf(v.z); o[3] = f2bf(v.w);
    *(u16x4*)&xb[i] = o;
    return;
  }
  if (id < 7196) {
    int t = id - 4124;
    const int bx = t & 1, by = (t >> 1) & 31, z = t >> 6;
    const int which = z >> 4, h = z & 15;
    const float* in = (which == 0 ? Wq : (which == 1 ? Wk : Wv)) + (size_t)h * 1024 * 64;
    u16* out = Wqkv_t + ((size_t)which * 1024 + h * 64) * 1024;   // [64][1024]
    const float sc = (which == 0) ? 0.18033688f : 1.0f;           // 0.125*log2e
    const int tx = tid & 31, ty = tid >> 5;
    const int r0 = by * 32, c0 = bx * 32;
    #pragma unroll
    for (int i = 0; i < 32; i += 8)
      tile[ty + i][tx] = f2bf(in[(size_t)(r0 + ty + i) * 64 + c0 + tx] * sc);
    __syncthreads();
    #pragma unroll
    for (int i = 0; i < 32; i += 8)
      out[(size_t)(c0 + ty + i) * 1024 + r0 + tx] = tile[tx][ty + i];
    return;
  }
  {
    int t0 = id - 7196;
    const float* in; u16* outp; int R, C, cx, ry;
    if (t0 < 1024)      { in = Wo; outp = Wo_t; R = 1024; C = 1024; cx = t0 & 31;  ry = t0 >> 5; }
    else if (t0 < 5120) { int t = t0 - 1024; in = W1; outp = W1_t; R = 1024; C = 4096; cx = t & 127; ry = t >> 7; }
    else                { int t = t0 - 5120; in = W2; outp = W2_t; R = 4096; C = 1024; cx = t & 31;  ry = t >> 5; }
    const int tx = tid & 31, ty = tid >> 5;
    const int r0 = ry * 32, c0 = cx * 32;
    #pragma unroll
    for (int i = 0; i < 32; i += 8)
      tile[ty + i][tx] = f2bf(in[(size_t)(r0 + ty + i) * C + c0 + tx]);
    __syncthreads();
    #pragma unroll
    for (int i = 0; i < 32; i += 8)
      outp[(size_t)(c0 + ty + i) * R + r0 + tx] = tile[tx][ty + i];
  }
}

// 256-tile XCD-chunked remap (T1). nwg = gX*gY must be %8==0.
__device__ __forceinline__ void xcd_tiles256(int& m0, int& n0) {
  const int gX = gridDim.x, gY = gridDim.y;
  int n = blockIdx.y * gX + blockIdx.x;
  int cpx = (gX * gY) >> 3;
  int t = (n & 7) * cpx + (n >> 3);
  n0 = (t / gY) * 256;
  m0 = (t % gY) * 256;
}

// ---------------------------------------------------------------------------
// gemm256: 256x256 tile, BK=64, 8 waves, counted-vmcnt pipeline + LDS
// XOR-swizzle (verified r8: 366->347us over drain0). SPLITK>=1: z-slice kz
// computes K/SPLITK cols; MODE 2 writes bf16 partials CONTIGUOUSLY at
// C + kz*M*N (no bias) — caller must reserve SPLITK*M*N u16 at C.
// Wait-count schedule is NT-independent (re-derived for NT=8/16/32).
// MODE 0: bias, 1: bias+relu, 2: split-K partial.
// ---------------------------------------------------------------------------
template <int MODE, int SPLITK>
__global__ __launch_bounds__(512, 2) void gemm256(
    const u16* __restrict__ A, const u16* __restrict__ Bt,
    const float* __restrict__ bias, u16* __restrict__ C,
    int M, int N, int K) {
  extern __shared__ __align__(16) u16 lds[];
  u16* As = lds;            // [2][256][64] (chunk s = rows s*64..s*64+63)
  u16* Bs = lds + 32768;
  const int tid = threadIdx.x;   // 0..511
  const int lane = tid & 63, wave = tid >> 6;
  const int lrow = lane & 15, quad = lane >> 4;
  int m0, n0;
  xcd_tiles256(m0, n0);
  const int Keff = K / SPLITK;
  const int kbase = (SPLITK > 1) ? (int)blockIdx.z * Keff : 0;

  const int sw = lrow & 7;                        // read-side swizzle key
  const int srow = tid >> 3;                      // staging row within chunk
  const int scol = ((tid & 7) ^ (srow & 7)) * 8;  // pre-swizzled source col
  const u16* gA = A  + (size_t)(m0 + srow) * K + kbase + scol;
  const u16* gB = Bt + (size_t)(n0 + srow) * K + kbase + scol;
  const int tid8 = tid * 8;

  f32x4 acc[16][2];
  #pragma unroll
  for (int i = 0; i < 16; ++i) {
    acc[i][0] = (f32x4){0.f, 0.f, 0.f, 0.f};
    acc[i][1] = (f32x4){0.f, 0.f, 0.f, 0.f};
  }

  const int NT = Keff >> 6;

  // prologue: stage step 0 -> buf 0 (B chunks 0..3 then A chunks 0..3)
  #pragma unroll
  for (int s = 0; s < 4; ++s)
    gll16(gB + (size_t)(s * 64) * K, Bs + s * 4096 + tid8);
  #pragma unroll
  for (int s = 0; s < 4; ++s)
    gll16(gA + (size_t)(s * 64) * K, As + s * 4096 + tid8);

#define DSA(fr, kh) (*(const bf16x8*)&Ab[((fr) * 16 + lrow) * 64 + ((((kh) * 4 + quad) ^ sw) * 8)])
#define DSB(fc, kh) (*(const bf16x8*)&Bb[(wave * 32 + (fc) * 16 + lrow) * 64 + ((((kh) * 4 + quad) ^ sw) * 8)])
#define STG_B(s) gll16(gB + koff + (size_t)((s) * 64) * K, Bd + (s) * 4096)
#define STG_A(s) gll16(gA + koff + (size_t)((s) * 64) * K, Ad + (s) * 4096)
#define KPHASE(P, VMSTR, STEXPR)                                              \
    asm volatile("s_waitcnt " VMSTR ::: "memory");                            \
    __builtin_amdgcn_s_barrier();                                             \
    asm volatile("" ::: "memory");                                            \
    {                                                                         \
      bf16x8 af[4][2];                                                        \
      if ((P) == 0) {                                                         \
        _Pragma("unroll")                                                     \
        for (int fc = 0; fc < 2; ++fc) {                                      \
          bfr[fc][0] = DSB(fc, 0);                                            \
          bfr[fc][1] = DSB(fc, 1);                                            \
        }                                                                     \
      }                                                                       \
      _Pragma("unroll")                                                       \
      for (int j = 0; j < 4; ++j) {                                           \
        af[j][0] = DSA((P) * 4 + j, 0);                                       \
        af[j][1] = DSA((P) * 4 + j, 1);                                       \
      }                                                                       \
      STEXPR                                                                  \
      __builtin_amdgcn_s_setprio(1);                                          \
      _Pragma("unroll")                                                       \
      for (int j = 0; j < 4; ++j) {                                           \
        _Pragma("unroll")                                                     \
        for (int fc = 0; fc < 2; ++fc) {                                      \
          acc[(P) * 4 + j][fc] = MFMA16(af[j][0], bfr[fc][0], acc[(P) * 4 + j][fc]); \
          acc[(P) * 4 + j][fc] = MFMA16(af[j][1], bfr[fc][1], acc[(P) * 4 + j][fc]); \
        }                                                                     \
      }                                                                       \
      __builtin_amdgcn_s_setprio(0);                                          \
    }

  for (int t = 0; t < NT - 1; ++t) {
    const int p = t & 1;
    const u16* Ab = As + p * 16384;
    const u16* Bb = Bs + p * 16384;
    u16* Ad = As + (p ^ 1) * 16384 + tid8;
    u16* Bd = Bs + (p ^ 1) * 16384 + tid8;
    const size_t koff = (size_t)(t + 1) * 64;
    bf16x8 bfr[2][2];
    KPHASE(0, "vmcnt(3)", STG_B(0); STG_B(1);)
    KPHASE(1, "vmcnt(4)", STG_B(2); STG_B(3);)
    KPHASE(2, "vmcnt(5)", STG_A(0); STG_A(1);)
    KPHASE(3, "vmcnt(6)", STG_A(2); STG_A(3);)
  }
  {
    const int p = (NT - 1) & 1;
    const u16* Ab = As + p * 16384;
    const u16* Bb = Bs + p * 16384;
    bf16x8 bfr[2][2];
    KPHASE(0, "vmcnt(3)", )
    KPHASE(1, "vmcnt(2)", )
    KPHASE(2, "vmcnt(1)", )
    KPHASE(3, "vmcnt(0)", )
  }
#undef DSA
#undef DSB
#undef STG_B
#undef STG_A
#undef KPHASE

  u16* Cz = (MODE == 2) ? C + (size_t)blockIdx.z * M * N : C;
  #pragma unroll
  for (int fr = 0; fr < 16; ++fr) {
    int rowb = m0 + fr * 16 + quad * 4;
    #pragma unroll
    for (int fc = 0; fc < 2; ++fc) {
      int col = n0 + wave * 32 + fc * 16 + lrow;
      float bv = (MODE == 2) ? 0.f : bias[col];
      #pragma unroll
      for (int r = 0; r < 4; ++r) {
        float v = acc[fr][fc][r] + bv;
        if (MODE == 1) v = fmaxf(v, 0.f);
        Cz[(size_t)(rowb + r) * N + col] = f2bf(v);
      }
    }
  }
}

// ---------------------------------------------------------------------------
// Flash attention — r5 form verbatim (75.5-77.5 us measured): 2 barriers/step,
// t=2 q-tiles/wave, 128 q-rows/block, grid (16,16,2), no setprio.
// Vt trimmed to [64][72]; p = exp2(z + madd) (Wq pre-scaled). LDS 36864 B.
// ---------------------------------------------------------------------------
__global__ __launch_bounds__(256) void attn_kernel(
    const u16* __restrict__ xqkv, const float* __restrict__ madd2,
    u16* __restrict__ ctx) {
  __shared__ __align__(16) u16 Ks[64][72];
  __shared__ __align__(16) u16 Vt[64][72];
  __shared__ __align__(16) u16 Ps[4][2][16][72];
  const int tid = threadIdx.x;
  const int lane = tid & 63;
  const int wave = tid >> 6;
  const int lrow = lane & 15;
  const int quad = lane >> 4;
  const int b = blockIdx.z, h = blockIdx.y;
  const int qb = blockIdx.x * 128 + wave * 16;
  const u16* Qp = xqkv + (size_t)b * 2048 * 3072 + h * 64;
  const u16* Kp = Qp + 1024;
  const u16* Vp = Qp + 2048;

  bf16x8 qa[2][2];
  #pragma unroll
  for (int t = 0; t < 2; ++t) {
    qa[t][0] = *(const bf16x8*)&Qp[(size_t)(qb + t * 64 + lrow) * 3072 + quad * 8];
    qa[t][1] = *(const bf16x8*)&Qp[(size_t)(qb + t * 64 + lrow) * 3072 + 32 + quad * 8];
  }

  f32x4 o[2][4];
  #pragma unroll
  for (int t = 0; t < 2; ++t)
    #pragma unroll
    for (int i = 0; i < 4; ++i) o[t][i] = (f32x4){0.f, 0.f, 0.f, 0.f};
  float rsum[2] = {0.f, 0.f};

  const int ks_row = tid >> 3, ks_col = (tid & 7) * 8;
  const int v_dg = tid >> 4;
  const int v_kp = tid & 15;
  const float* maddb = madd2 + b * 2048;

  u16x8 kreg[2];
  u16x4 va[2], vb[2];
  #pragma unroll
  for (int sh = 0; sh < 2; ++sh) {
    kreg[sh] = *(const u16x8*)&Kp[(size_t)(sh * 32 + ks_row) * 3072 + ks_col];
    va[sh] = *(const u16x4*)&Vp[(size_t)(sh * 32 + 2 * v_kp) * 3072 + v_dg * 4];
    vb[sh] = *(const u16x4*)&Vp[(size_t)(sh * 32 + 2 * v_kp + 1) * 3072 + v_dg * 4];
  }

  for (int s0 = 0; s0 < 2048; s0 += 64) {
    __syncthreads();
    #pragma unroll
    for (int sh = 0; sh < 2; ++sh) {
      *(u16x8*)&Ks[sh * 32 + ks_row][ks_col] = kreg[sh];
      #pragma unroll
      for (int j = 0; j < 4; ++j) {
        u32 pk = ((u32)vb[sh][j] << 16) | (u32)va[sh][j];
        *(u32*)&Vt[v_dg * 4 + j][sh * 32 + 2 * v_kp] = pk;
      }
    }
    __syncthreads();
    if (s0 + 64 < 2048) {
      #pragma unroll
      for (int sh = 0; sh < 2; ++sh) {
        int sb = s0 + 64 + sh * 32;
        kreg[sh] = *(const u16x8*)&Kp[(size_t)(sb + ks_row) * 3072 + ks_col];
        va[sh] = *(const u16x4*)&Vp[(size_t)(sb + 2 * v_kp) * 3072 + v_dg * 4];
        vb[sh] = *(const u16x4*)&Vp[(size_t)(sb + 2 * v_kp + 1) * 3072 + v_dg * 4];
      }
    }

    bf16x8 kf[4][2], vf[4][2];
    #pragma unroll
    for (int kb = 0; kb < 4; ++kb) {
      kf[kb][0] = *(const bf16x8*)&Ks[kb * 16 + lrow][quad * 8];
      kf[kb][1] = *(const bf16x8*)&Ks[kb * 16 + lrow][32 + quad * 8];
    }
    #pragma unroll
    for (int nb = 0; nb < 4; ++nb) {
      vf[nb][0] = *(const bf16x8*)&Vt[nb * 16 + lrow][quad * 8];
      vf[nb][1] = *(const bf16x8*)&Vt[nb * 16 + lrow][32 + quad * 8];
    }

    #pragma unroll
    for (int t = 0; t < 2; ++t) {
      #pragma unroll
      for (int kb = 0; kb < 4; ++kb) {
        f32x4 z = (f32x4){0.f, 0.f, 0.f, 0.f};
        z = MFMA16(kf[kb][0], qa[t][0], z);
        z = MFMA16(kf[kb][1], qa[t][1], z);
        f32x4 m4 = *(const f32x4*)&maddb[s0 + kb * 16 + quad * 4];
        u32 pb[4];
        #pragma unroll
        for (int r = 0; r < 4; ++r) {
          float p = fast_exp2(z[r] + m4[r]);
          rsum[t] += p;
          union { float f; u32 u; } cv; cv.f = p;
          pb[r] = cv.u + 0x8000u;
        }
        u32x2 w2;
        w2[0] = __builtin_amdgcn_perm(pb[1], pb[0], 0x07060302);
        w2[1] = __builtin_amdgcn_perm(pb[3], pb[2], 0x07060302);
        *(u32x2*)&Ps[wave][t][lrow][kb * 16 + quad * 4] = w2;
      }
      #pragma unroll
      for (int kh = 0; kh < 2; ++kh) {
        bf16x8 pa = *(const bf16x8*)&Ps[wave][t][lrow][kh * 32 + quad * 8];
        #pragma unroll
        for (int nb = 0; nb < 4; ++nb)
          o[t][nb] = MFMA16(pa, vf[nb][kh], o[t][nb]);
      }
    }
  }

  #pragma unroll
  for (int t = 0; t < 2; ++t) {
    float rs = rsum[t];
    rs += __shfl_xor(rs, 16, 64);
    rs += __shfl_xor(rs, 32, 64);
    float inv = 1.f / fmaxf(rs, 1e-30f);
    #pragma unroll
    for (int r = 0; r < 4; ++r) {
      float invq = __shfl(inv, quad * 4 + r, 64);
      int q = qb + t * 64 + quad * 4 + r;
      #pragma unroll
      for (int nb = 0; nb < 4; ++nb) {
        float v = o[t][nb][r] * invq;
        ctx[((size_t)b * 2048 + q) * 1024 + h * 64 + nb * 16 + lrow] = f2bf(v);
      }
    }
  }
}

// ---------------------------------------------------------------------------
// out = LayerNorm(x + p0 + p1 + cb) * g + b  (2-partial combine fused in).
// ---------------------------------------------------------------------------
template <int IN_BF, int OUT_BF>
__global__ __launch_bounds__(256) void add_ln2p(
    const void* __restrict__ xa_, const u16* __restrict__ p0,
    const u16* __restrict__ p1, const float* __restrict__ cb,
    const float* __restrict__ g, const float* __restrict__ bb,
    void* __restrict__ outp_) {
  __shared__ float red[8];
  const int tid = threadIdx.x;
  const size_t base = (size_t)blockIdx.x * 1024;
  const float* xf = (const float*)xa_;
  const u16*   xb = (const u16*)xa_;
  float v[4];
  float s = 0.f;
  #pragma unroll
  for (int i = 0; i < 4; ++i) {
    int c = i * 256 + tid;
    float xv = IN_BF ? bf2f(xb[base + c]) : xf[base + c];
    v[i] = xv + bf2f(p0[base + c]) + bf2f(p1[base + c]) + cb[c];
    s += v[i];
  }
  #pragma unroll
  for (int off = 32; off > 0; off >>= 1) s += __shfl_down(s, off, 64);
  if ((tid & 63) == 0) red[tid >> 6] = s;
  __syncthreads();
  float mean = (red[0] + red[1] + red[2] + red[3]) * (1.f / 1024.f);
  float s2 = 0.f;
  #pragma unroll
  for (int i = 0; i < 4; ++i) { float d = v[i] - mean; s2 += d * d; }
  #pragma unroll
  for (int off = 32; off > 0; off >>= 1) s2 += __shfl_down(s2, off, 64);
  if ((tid & 63) == 0) red[4 + (tid >> 6)] = s2;
  __syncthreads();
  float var = (red[4] + red[5] + red[6] + red[7]) * (1.f / 1024.f);
  float rstd = rsqrtf(var + 1e-5f);
  #pragma unroll
  for (int i = 0; i < 4; ++i) {
    int c = i * 256 + tid;
    float r = (v[i] - mean) * rstd * g[c] + bb[c];
    if (OUT_BF) ((u16*)outp_)[base + c] = f2bf(r);
    else        ((float*)outp_)[base + c] = r;
  }
}

// ---------------------------------------------------------------------------
extern "C" void kernel_launch(void* const* d_in, const int* in_sizes, int n_in,
                              void* d_out, int out_size, void* d_ws, size_t ws_size,
                              hipStream_t stream) {
  (void)in_sizes; (void)n_in; (void)out_size; (void)ws_size;
  const float* x    = (const float*)d_in[0];
  const int*   mask = (const int*)d_in[1];
  const float* Wq   = (const float*)d_in[2];
  const float* bq   = (const float*)d_in[3];
  const float* Wk   = (const float*)d_in[4];
  const float* bk   = (const float*)d_in[5];
  const float* Wv   = (const float*)d_in[6];
  const float* bv   = (const float*)d_in[7];
  const float* Wo   = (const float*)d_in[8];
  const float* bo   = (const float*)d_in[9];
  const float* ln1g = (const float*)d_in[10];
  const float* ln1b = (const float*)d_in[11];
  const float* ln2g = (const float*)d_in[12];
  const float* ln2b = (const float*)d_in[13];
  const float* W1   = (const float*)d_in[14];
  const float* b1   = (const float*)d_in[15];
  const float* W2   = (const float*)d_in[16];
  const float* b2   = (const float*)d_in[17];
  float* out = (float*)d_out;

  char* ws = (char*)d_ws;
  u16*   Wqkv_t = (u16*)(ws + 0);           // 6 MB [prep->QKV]; dead after
  u16*   fp     = (u16*)(ws + 0);           // FF2 partials [0,16M) — Wqkv_t/
                                            //   Wo_t/W1_t all dead by FF2;
                                            //   ends exactly at W2_t (16M)
  u16*   Wo_t   = (u16*)(ws + 6291456);     // 2 MB [prep->Wo]
  u16*   W1_t   = (u16*)(ws + 8388608);     // 8 MB [prep->FF1]
  u16*   W2_t   = (u16*)(ws + 16777216);    // 8 MB [prep->FF2] — NOT in fp
  u16*   xqkv   = (u16*)(ws + 25165824);    // 24 MB [QKV->attn]
  u16*   wp     = (u16*)(ws + 25165824);    // Wo partials 2x8 MB (xqkv dead),
                                            //   contiguous: wp, wp+4194304
  u16*   xb     = (u16*)(ws + 50331648);    // 8 MB [prep->QKV]
  u16*   ctx    = (u16*)(ws + 50331648);    // 8 MB [attn->Wo] (xb dead)
  u16*   ff1    = (u16*)(ws + 25165824);    // 32 MB [FF1->FF2] (wp dead
                                            //   after LN1; spans xqkv+ctx)
  u16*   hbuf   = (u16*)(ws + 67108864);    // 8 MB [LN1->LN2 residual]
  float* biasq  = (float*)(ws + 75497472);  // 3072 f32
  float* madd2  = (float*)(ws + 75509760);  // 4096 f32  (total ~75.5 MB)

  prep_all<<<16412, 256, 0, stream>>>(bq, bk, bv, mask, biasq, madd2,
                                      x, xb, Wq, Wk, Wv, Wqkv_t,
                                      Wo, W1, W2, Wo_t, W1_t, W2_t);

  // QKV: 256^2 counted-vmcnt template, grid 12x16 = 192 blocks (NT=16)
  gemm256<0, 1><<<dim3(12, 16), 512, 131072, stream>>>(xb, Wqkv_t, biasq, xqkv,
                                                       4096, 3072, 1024);
  attn_kernel<<<dim3(16, 16, 2), 256, 0, stream>>>(xqkv, madd2, ctx);
  // Wo: 256^2 template, split-K=2 (Keff=512, NT=8), contiguous partials
  // into dead xqkv space, combined by add_ln2p.
  gemm256<2, 2><<<dim3(4, 16, 2), 512, 131072, stream>>>(ctx, Wo_t, nullptr, wp,
                                                         4096, 1024, 1024);
  add_ln2p<0, 1><<<4096, 256, 0, stream>>>(x, wp, wp + 4194304, bo,
                                           ln1g, ln1b, hbuf);
  // FF1: 256^2 template with fused relu, grid 16x16 = 256 blocks (NT=16)
  gemm256<1, 1><<<dim3(16, 16), 512, 131072, stream>>>(hbuf, W1_t, b1, ff1,
                                                       4096, 4096, 1024);
  // FF2: 256^2 template, split-K=2 (Keff=2048, NT=32), contiguous partials
  // at [0,16M) (all weights there dead), combined by add_ln2p.
  gemm256<2, 2><<<dim3(4, 16, 2), 512, 131072, stream>>>(ff1, W2_t, nullptr, fp,
                                                         4096, 1024, 4096);
  add_ln2p<1, 0><<<4096, 256, 0, stream>>>(hbuf, fp, fp + 4194304, b2,
                                           ln2g, ln2b, out);
}

// Round 11
// 341.199 us; speedup vs baseline: 1.0392x; 1.0392x over previous
//
#include <hip/hip_runtime.h>
#include <cstdint>
#include <cstddef>

typedef unsigned short u16;
typedef unsigned int   u32;
typedef unsigned short u16x4 __attribute__((ext_vector_type(4)));
typedef unsigned short u16x8 __attribute__((ext_vector_type(8)));
typedef unsigned int   u32x2 __attribute__((ext_vector_type(2)));
typedef __bf16 bf16x8 __attribute__((ext_vector_type(8)));
typedef float f32x4 __attribute__((ext_vector_type(4)));

#define MFMA16(a, b, c) __builtin_amdgcn_mfma_f32_16x16x32_bf16((a), (b), (c), 0, 0, 0)

__device__ __forceinline__ float bf2f(u16 h) {
  union { unsigned u; float f; } v; v.u = ((unsigned)h) << 16; return v.f;
}
__device__ __forceinline__ u16 f2bf(float f) {
  union { float f; unsigned u; } v; v.f = f;
  unsigned r = v.u + 0x7fffu + ((v.u >> 16) & 1u);
  return (u16)(r >> 16);
}
__device__ __forceinline__ void gll16(const u16* g, u16* l) {
  __builtin_amdgcn_global_load_lds(
      (const __attribute__((address_space(1))) void*)g,
      (__attribute__((address_space(3))) void*)l, 16, 0, 0);
}
__device__ __forceinline__ float fast_exp2(float x) {
#if __has_builtin(__builtin_amdgcn_exp2f)
  return __builtin_amdgcn_exp2f(x);
#else
  return exp2f(x);
#endif
}

// ---------------------------------------------------------------------------
// Fused prologue: one dispatch replaces prep_small + cvt_x + transpose_qkv +
// transpose_w. Block-id ranges:
//   [0,28)        prep_small   [28,4124)  cvt_x
//   [4124,7196)   transpose_qkv (Wq pre-scaled by 0.125*log2e)
//   [7196,16412)  transpose_w
// ---------------------------------------------------------------------------
__global__ __launch_bounds__(256) void prep_all(
    const float* __restrict__ bq, const float* __restrict__ bk,
    const float* __restrict__ bv, const int* __restrict__ mask,
    float* __restrict__ biasq, float* __restrict__ madd2,
    const float* __restrict__ x, u16* __restrict__ xb,
    const float* __restrict__ Wq, const float* __restrict__ Wk,
    const float* __restrict__ Wv, u16* __restrict__ Wqkv_t,
    const float* __restrict__ Wo, const float* __restrict__ W1,
    const float* __restrict__ W2, u16* __restrict__ Wo_t,
    u16* __restrict__ W1_t, u16* __restrict__ W2_t) {
  __shared__ u16 tile[32][33];
  const int id = blockIdx.x;
  const int tid = threadIdx.x;

  if (id < 28) {
    int i = id * 256 + tid;
    if (i < 3072) {
      biasq[i] = (i < 1024) ? bq[i] * 0.18033688f
                            : (i < 2048 ? bk[i - 1024] : bv[i - 2048]);
    } else if (i < 7168) {
      int j = i - 3072;
      madd2[j] = mask[j] ? -23.083120f : -1.442695e9f;  // (-16|-1e9)*log2e
    }
    return;
  }
  if (id < 4124) {
    int i = ((id - 28) * 256 + tid) * 4;
    const float4 v = *(const float4*)&x[i];
    u16x4 o;
    o[0] = f2bf(v.x); o[1] = f2bf(v.y); o[2] = f2bf(v.z); o[3] = f2bf(v.w);
    *(u16x4*)&xb[i] = o;
    return;
  }
  if (id < 7196) {
    int t = id - 4124;
    const int bx = t & 1, by = (t >> 1) & 31, z = t >> 6;
    const int which = z >> 4, h = z & 15;
    const float* in = (which == 0 ? Wq : (which == 1 ? Wk : Wv)) + (size_t)h * 1024 * 64;
    u16* out = Wqkv_t + ((size_t)which * 1024 + h * 64) * 1024;   // [64][1024]
    const float sc = (which == 0) ? 0.18033688f : 1.0f;           // 0.125*log2e
    const int tx = tid & 31, ty = tid >> 5;
    const int r0 = by * 32, c0 = bx * 32;
    #pragma unroll
    for (int i = 0; i < 32; i += 8)
      tile[ty + i][tx] = f2bf(in[(size_t)(r0 + ty + i) * 64 + c0 + tx] * sc);
    __syncthreads();
    #pragma unroll
    for (int i = 0; i < 32; i += 8)
      out[(size_t)(c0 + ty + i) * 1024 + r0 + tx] = tile[tx][ty + i];
    return;
  }
  {
    int t0 = id - 7196;
    const float* in; u16* outp; int R, C, cx, ry;
    if (t0 < 1024)      { in = Wo; outp = Wo_t; R = 1024; C = 1024; cx = t0 & 31;  ry = t0 >> 5; }
    else if (t0 < 5120) { int t = t0 - 1024; in = W1; outp = W1_t; R = 1024; C = 4096; cx = t & 127; ry = t >> 7; }
    else                { int t = t0 - 5120; in = W2; outp = W2_t; R = 4096; C = 1024; cx = t & 31;  ry = t >> 5; }
    const int tx = tid & 31, ty = tid >> 5;
    const int r0 = ry * 32, c0 = cx * 32;
    #pragma unroll
    for (int i = 0; i < 32; i += 8)
      tile[ty + i][tx] = f2bf(in[(size_t)(r0 + ty + i) * C + c0 + tx]);
    __syncthreads();
    #pragma unroll
    for (int i = 0; i < 32; i += 8)
      outp[(size_t)(c0 + ty + i) * R + r0 + tx] = tile[tx][ty + i];
  }
}

// ---------------------------------------------------------------------------
// gemm256: BM=256 x BN=NB*64 tile, BK=64, 8 waves, counted-vmcnt pipeline +
// LDS XOR-swizzle. NB = number of 64-row B chunks per K-step (4 -> BN=256,
// verified r8/r10; 2 -> BN=128, same wait constants — rederived: phase needs
// {B0,B1,A0}/{A1}/{A2}/{A3} vs issue order B*,A0..A3 give vmcnt(3/4/5/6),
// epilogue 3/2/1/0, identical to NB=4).
// SPLITK>=1: z-slice computes K/SPLITK cols; MODE 2 writes bf16 partials
// CONTIGUOUSLY at C + z*M*N (no bias).
// LDS: A 2x16384 u16 + B 2x(NB*4096) u16 = 65536 + NB*16384 bytes.
// MODE 0: bias, 1: bias+relu, 2: split-K partial.
// ---------------------------------------------------------------------------
template <int MODE, int SPLITK, int NB>
__global__ __launch_bounds__(512, 2) void gemm256(
    const u16* __restrict__ A, const u16* __restrict__ Bt,
    const float* __restrict__ bias, u16* __restrict__ C,
    int M, int N, int K) {
  extern __shared__ __align__(16) u16 lds[];
  u16* As = lds;                 // [2][256][64]
  u16* Bs = lds + 32768;         // [2][NB*64][64]
  constexpr int FC = NB / 2;     // per-wave 16-col blocks
  const int tid = threadIdx.x;   // 0..511
  const int lane = tid & 63, wave = tid >> 6;
  const int lrow = lane & 15, quad = lane >> 4;

  // XCD-chunked remap (T1); nwg = gX*gY must be %8==0.
  int m0, n0;
  {
    const int gX = gridDim.x, gY = gridDim.y;
    int n = blockIdx.y * gX + blockIdx.x;
    int cpx = (gX * gY) >> 3;
    int t = (n & 7) * cpx + (n >> 3);
    n0 = (t / gY) * (NB * 64);
    m0 = (t % gY) * 256;
  }
  const int Keff = K / SPLITK;
  const int kbase = (SPLITK > 1) ? (int)blockIdx.z * Keff : 0;

  const int sw = lrow & 7;                        // read-side swizzle key
  const int srow = tid >> 3;                      // staging row within chunk
  const int scol = ((tid & 7) ^ (srow & 7)) * 8;  // pre-swizzled source col
  const u16* gA = A  + (size_t)(m0 + srow) * K + kbase + scol;
  const u16* gB = Bt + (size_t)(n0 + srow) * K + kbase + scol;
  const int tid8 = tid * 8;

  f32x4 acc[16][FC];
  #pragma unroll
  for (int i = 0; i < 16; ++i)
    #pragma unroll
    for (int j = 0; j < FC; ++j)
      acc[i][j] = (f32x4){0.f, 0.f, 0.f, 0.f};

  const int NT = Keff >> 6;

  // prologue: stage step 0 -> buf 0 (B chunks 0..NB-1 then A chunks 0..3)
  #pragma unroll
  for (int s = 0; s < NB; ++s)
    gll16(gB + (size_t)(s * 64) * K, Bs + s * 4096 + tid8);
  #pragma unroll
  for (int s = 0; s < 4; ++s)
    gll16(gA + (size_t)(s * 64) * K, As + s * 4096 + tid8);

#define DSA(fr, kh) (*(const bf16x8*)&Ab[((fr) * 16 + lrow) * 64 + ((((kh) * 4 + quad) ^ sw) * 8)])
#define DSB(fc, kh) (*(const bf16x8*)&Bb[(wave * (NB * 8) + (fc) * 16 + lrow) * 64 + ((((kh) * 4 + quad) ^ sw) * 8)])
#define STG_B(s) gll16(gB + koff + (size_t)((s) * 64) * K, Bd + (s) * 4096)
#define STG_A(s) gll16(gA + koff + (size_t)((s) * 64) * K, Ad + (s) * 4096)
#define KPHASE(P, VMSTR, STEXPR)                                              \
    asm volatile("s_waitcnt " VMSTR ::: "memory");                            \
    __builtin_amdgcn_s_barrier();                                             \
    asm volatile("" ::: "memory");                                            \
    {                                                                         \
      bf16x8 af[4][2];                                                        \
      if ((P) == 0) {                                                         \
        _Pragma("unroll")                                                     \
        for (int fc = 0; fc < FC; ++fc) {                                     \
          bfr[fc][0] = DSB(fc, 0);                                            \
          bfr[fc][1] = DSB(fc, 1);                                            \
        }                                                                     \
      }                                                                       \
      _Pragma("unroll")                                                       \
      for (int j = 0; j < 4; ++j) {                                           \
        af[j][0] = DSA((P) * 4 + j, 0);                                       \
        af[j][1] = DSA((P) * 4 + j, 1);                                       \
      }                                                                       \
      STEXPR                                                                  \
      __builtin_amdgcn_s_setprio(1);                                          \
      _Pragma("unroll")                                                       \
      for (int j = 0; j < 4; ++j) {                                           \
        _Pragma("unroll")                                                     \
        for (int fc = 0; fc < FC; ++fc) {                                     \
          acc[(P) * 4 + j][fc] = MFMA16(af[j][0], bfr[fc][0], acc[(P) * 4 + j][fc]); \
          acc[(P) * 4 + j][fc] = MFMA16(af[j][1], bfr[fc][1], acc[(P) * 4 + j][fc]); \
        }                                                                     \
      }                                                                       \
      __builtin_amdgcn_s_setprio(0);                                          \
    }

  for (int t = 0; t < NT - 1; ++t) {
    const int p = t & 1;
    const u16* Ab = As + p * 16384;
    const u16* Bb = Bs + p * (NB * 4096);
    u16* Ad = As + (p ^ 1) * 16384 + tid8;
    u16* Bd = Bs + (p ^ 1) * (NB * 4096) + tid8;
    const size_t koff = (size_t)(t + 1) * 64;
    bf16x8 bfr[FC][2];
    KPHASE(0, "vmcnt(3)", { STG_B(0); STG_B(1); })
    KPHASE(1, "vmcnt(4)", { if constexpr (NB == 4) { STG_B(2); STG_B(3); }
                            else { STG_A(0); STG_A(1); } })
    KPHASE(2, "vmcnt(5)", { if constexpr (NB == 4) { STG_A(0); STG_A(1); }
                            else { STG_A(2); STG_A(3); } })
    KPHASE(3, "vmcnt(6)", { if constexpr (NB == 4) { STG_A(2); STG_A(3); } })
  }
  {
    const int p = (NT - 1) & 1;
    const u16* Ab = As + p * 16384;
    const u16* Bb = Bs + p * (NB * 4096);
    bf16x8 bfr[FC][2];
    KPHASE(0, "vmcnt(3)", )
    KPHASE(1, "vmcnt(2)", )
    KPHASE(2, "vmcnt(1)", )
    KPHASE(3, "vmcnt(0)", )
  }
#undef DSA
#undef DSB
#undef STG_B
#undef STG_A
#undef KPHASE

  u16* Cz = (MODE == 2) ? C + (size_t)blockIdx.z * M * N : C;
  #pragma unroll
  for (int fr = 0; fr < 16; ++fr) {
    int rowb = m0 + fr * 16 + quad * 4;
    #pragma unroll
    for (int fc = 0; fc < FC; ++fc) {
      int col = n0 + wave * (NB * 8) + fc * 16 + lrow;
      float bv = (MODE == 2) ? 0.f : bias[col];
      #pragma unroll
      for (int r = 0; r < 4; ++r) {
        float v = acc[fr][fc][r] + bv;
        if (MODE == 1) v = fmaxf(v, 0.f);
        Cz[(size_t)(rowb + r) * N + col] = f2bf(v);
      }
    }
  }
}

// ---------------------------------------------------------------------------
// Flash attention — r5 form verbatim (74.3-77.8 us measured): 2 barriers/step,
// t=2 q-tiles/wave, 128 q-rows/block, grid (16,16,2), no setprio.
// Vt trimmed to [64][72]; p = exp2(z + madd) (Wq pre-scaled). LDS 36864 B.
// ---------------------------------------------------------------------------
__global__ __launch_bounds__(256) void attn_kernel(
    const u16* __restrict__ xqkv, const float* __restrict__ madd2,
    u16* __restrict__ ctx) {
  __shared__ __align__(16) u16 Ks[64][72];
  __shared__ __align__(16) u16 Vt[64][72];
  __shared__ __align__(16) u16 Ps[4][2][16][72];
  const int tid = threadIdx.x;
  const int lane = tid & 63;
  const int wave = tid >> 6;
  const int lrow = lane & 15;
  const int quad = lane >> 4;
  const int b = blockIdx.z, h = blockIdx.y;
  const int qb = blockIdx.x * 128 + wave * 16;
  const u16* Qp = xqkv + (size_t)b * 2048 * 3072 + h * 64;
  const u16* Kp = Qp + 1024;
  const u16* Vp = Qp + 2048;

  bf16x8 qa[2][2];
  #pragma unroll
  for (int t = 0; t < 2; ++t) {
    qa[t][0] = *(const bf16x8*)&Qp[(size_t)(qb + t * 64 + lrow) * 3072 + quad * 8];
    qa[t][1] = *(const bf16x8*)&Qp[(size_t)(qb + t * 64 + lrow) * 3072 + 32 + quad * 8];
  }

  f32x4 o[2][4];
  #pragma unroll
  for (int t = 0; t < 2; ++t)
    #pragma unroll
    for (int i = 0; i < 4; ++i) o[t][i] = (f32x4){0.f, 0.f, 0.f, 0.f};
  float rsum[2] = {0.f, 0.f};

  const int ks_row = tid >> 3, ks_col = (tid & 7) * 8;
  const int v_dg = tid >> 4;
  const int v_kp = tid & 15;
  const float* maddb = madd2 + b * 2048;

  u16x8 kreg[2];
  u16x4 va[2], vb[2];
  #pragma unroll
  for (int sh = 0; sh < 2; ++sh) {
    kreg[sh] = *(const u16x8*)&Kp[(size_t)(sh * 32 + ks_row) * 3072 + ks_col];
    va[sh] = *(const u16x4*)&Vp[(size_t)(sh * 32 + 2 * v_kp) * 3072 + v_dg * 4];
    vb[sh] = *(const u16x4*)&Vp[(size_t)(sh * 32 + 2 * v_kp + 1) * 3072 + v_dg * 4];
  }

  for (int s0 = 0; s0 < 2048; s0 += 64) {
    __syncthreads();
    #pragma unroll
    for (int sh = 0; sh < 2; ++sh) {
      *(u16x8*)&Ks[sh * 32 + ks_row][ks_col] = kreg[sh];
      #pragma unroll
      for (int j = 0; j < 4; ++j) {
        u32 pk = ((u32)vb[sh][j] << 16) | (u32)va[sh][j];
        *(u32*)&Vt[v_dg * 4 + j][sh * 32 + 2 * v_kp] = pk;
      }
    }
    __syncthreads();
    if (s0 + 64 < 2048) {
      #pragma unroll
      for (int sh = 0; sh < 2; ++sh) {
        int sb = s0 + 64 + sh * 32;
        kreg[sh] = *(const u16x8*)&Kp[(size_t)(sb + ks_row) * 3072 + ks_col];
        va[sh] = *(const u16x4*)&Vp[(size_t)(sb + 2 * v_kp) * 3072 + v_dg * 4];
        vb[sh] = *(const u16x4*)&Vp[(size_t)(sb + 2 * v_kp + 1) * 3072 + v_dg * 4];
      }
    }

    bf16x8 kf[4][2], vf[4][2];
    #pragma unroll
    for (int kb = 0; kb < 4; ++kb) {
      kf[kb][0] = *(const bf16x8*)&Ks[kb * 16 + lrow][quad * 8];
      kf[kb][1] = *(const bf16x8*)&Ks[kb * 16 + lrow][32 + quad * 8];
    }
    #pragma unroll
    for (int nb = 0; nb < 4; ++nb) {
      vf[nb][0] = *(const bf16x8*)&Vt[nb * 16 + lrow][quad * 8];
      vf[nb][1] = *(const bf16x8*)&Vt[nb * 16 + lrow][32 + quad * 8];
    }

    #pragma unroll
    for (int t = 0; t < 2; ++t) {
      #pragma unroll
      for (int kb = 0; kb < 4; ++kb) {
        f32x4 z = (f32x4){0.f, 0.f, 0.f, 0.f};
        z = MFMA16(kf[kb][0], qa[t][0], z);
        z = MFMA16(kf[kb][1], qa[t][1], z);
        f32x4 m4 = *(const f32x4*)&maddb[s0 + kb * 16 + quad * 4];
        u32 pb[4];
        #pragma unroll
        for (int r = 0; r < 4; ++r) {
          float p = fast_exp2(z[r] + m4[r]);
          rsum[t] += p;
          union { float f; u32 u; } cv; cv.f = p;
          pb[r] = cv.u + 0x8000u;
        }
        u32x2 w2;
        w2[0] = __builtin_amdgcn_perm(pb[1], pb[0], 0x07060302);
        w2[1] = __builtin_amdgcn_perm(pb[3], pb[2], 0x07060302);
        *(u32x2*)&Ps[wave][t][lrow][kb * 16 + quad * 4] = w2;
      }
      #pragma unroll
      for (int kh = 0; kh < 2; ++kh) {
        bf16x8 pa = *(const bf16x8*)&Ps[wave][t][lrow][kh * 32 + quad * 8];
        #pragma unroll
        for (int nb = 0; nb < 4; ++nb)
          o[t][nb] = MFMA16(pa, vf[nb][kh], o[t][nb]);
      }
    }
  }

  #pragma unroll
  for (int t = 0; t < 2; ++t) {
    float rs = rsum[t];
    rs += __shfl_xor(rs, 16, 64);
    rs += __shfl_xor(rs, 32, 64);
    float inv = 1.f / fmaxf(rs, 1e-30f);
    #pragma unroll
    for (int r = 0; r < 4; ++r) {
      float invq = __shfl(inv, quad * 4 + r, 64);
      int q = qb + t * 64 + quad * 4 + r;
      #pragma unroll
      for (int nb = 0; nb < 4; ++nb) {
        float v = o[t][nb][r] * invq;
        ctx[((size_t)b * 2048 + q) * 1024 + h * 64 + nb * 16 + lrow] = f2bf(v);
      }
    }
  }
}

// ---------------------------------------------------------------------------
// out = LayerNorm(x + p0 + p1 + cb) * g + b  (2-partial combine fused in).
// ---------------------------------------------------------------------------
template <int IN_BF, int OUT_BF>
__global__ __launch_bounds__(256) void add_ln2p(
    const void* __restrict__ xa_, const u16* __restrict__ p0,
    const u16* __restrict__ p1, const float* __restrict__ cb,
    const float* __restrict__ g, const float* __restrict__ bb,
    void* __restrict__ outp_) {
  __shared__ float red[8];
  const int tid = threadIdx.x;
  const size_t base = (size_t)blockIdx.x * 1024;
  const float* xf = (const float*)xa_;
  const u16*   xb = (const u16*)xa_;
  float v[4];
  float s = 0.f;
  #pragma unroll
  for (int i = 0; i < 4; ++i) {
    int c = i * 256 + tid;
    float xv = IN_BF ? bf2f(xb[base + c]) : xf[base + c];
    v[i] = xv + bf2f(p0[base + c]) + bf2f(p1[base + c]) + cb[c];
    s += v[i];
  }
  #pragma unroll
  for (int off = 32; off > 0; off >>= 1) s += __shfl_down(s, off, 64);
  if ((tid & 63) == 0) red[tid >> 6] = s;
  __syncthreads();
  float mean = (red[0] + red[1] + red[2] + red[3]) * (1.f / 1024.f);
  float s2 = 0.f;
  #pragma unroll
  for (int i = 0; i < 4; ++i) { float d = v[i] - mean; s2 += d * d; }
  #pragma unroll
  for (int off = 32; off > 0; off >>= 1) s2 += __shfl_down(s2, off, 64);
  if ((tid & 63) == 0) red[4 + (tid >> 6)] = s2;
  __syncthreads();
  float var = (red[4] + red[5] + red[6] + red[7]) * (1.f / 1024.f);
  float rstd = rsqrtf(var + 1e-5f);
  #pragma unroll
  for (int i = 0; i < 4; ++i) {
    int c = i * 256 + tid;
    float r = (v[i] - mean) * rstd * g[c] + bb[c];
    if (OUT_BF) ((u16*)outp_)[base + c] = f2bf(r);
    else        ((float*)outp_)[base + c] = r;
  }
}

// ---------------------------------------------------------------------------
extern "C" void kernel_launch(void* const* d_in, const int* in_sizes, int n_in,
                              void* d_out, int out_size, void* d_ws, size_t ws_size,
                              hipStream_t stream) {
  (void)in_sizes; (void)n_in; (void)out_size; (void)ws_size;
  const float* x    = (const float*)d_in[0];
  const int*   mask = (const int*)d_in[1];
  const float* Wq   = (const float*)d_in[2];
  const float* bq   = (const float*)d_in[3];
  const float* Wk   = (const float*)d_in[4];
  const float* bk   = (const float*)d_in[5];
  const float* Wv   = (const float*)d_in[6];
  const float* bv   = (const float*)d_in[7];
  const float* Wo   = (const float*)d_in[8];
  const float* bo   = (const float*)d_in[9];
  const float* ln1g = (const float*)d_in[10];
  const float* ln1b = (const float*)d_in[11];
  const float* ln2g = (const float*)d_in[12];
  const float* ln2b = (const float*)d_in[13];
  const float* W1   = (const float*)d_in[14];
  const float* b1   = (const float*)d_in[15];
  const float* W2   = (const float*)d_in[16];
  const float* b2   = (const float*)d_in[17];
  float* out = (float*)d_out;

  char* ws = (char*)d_ws;
  u16*   Wqkv_t = (u16*)(ws + 0);           // 6 MB [prep->QKV]; dead after
  u16*   fp     = (u16*)(ws + 0);           // FF2 partials [0,16M) — Wqkv_t/
                                            //   Wo_t/W1_t all dead by FF2;
                                            //   ends exactly at W2_t (16M)
  u16*   Wo_t   = (u16*)(ws + 6291456);     // 2 MB [prep->Wo]
  u16*   W1_t   = (u16*)(ws + 8388608);     // 8 MB [prep->FF1]
  u16*   W2_t   = (u16*)(ws + 16777216);    // 8 MB [prep->FF2] — NOT in fp
  u16*   xqkv   = (u16*)(ws + 25165824);    // 24 MB [QKV->attn]
  u16*   wp     = (u16*)(ws + 25165824);    // Wo partials 2x8 MB (xqkv dead),
                                            //   contiguous: wp, wp+4194304
  u16*   xb     = (u16*)(ws + 50331648);    // 8 MB [prep->QKV]
  u16*   ctx    = (u16*)(ws + 50331648);    // 8 MB [attn->Wo] (xb dead)
  u16*   ff1    = (u16*)(ws + 25165824);    // 32 MB [FF1->FF2] (wp dead
                                            //   after LN1; spans xqkv+ctx)
  u16*   hbuf   = (u16*)(ws + 67108864);    // 8 MB [LN1->LN2 residual]
  float* biasq  = (float*)(ws + 75497472);  // 3072 f32
  float* madd2  = (float*)(ws + 75509760);  // 4096 f32  (total ~75.5 MB)

  prep_all<<<16412, 256, 0, stream>>>(bq, bk, bv, mask, biasq, madd2,
                                      x, xb, Wq, Wk, Wv, Wqkv_t,
                                      Wo, W1, W2, Wo_t, W1_t, W2_t);

  // QKV: BN=256 template (r8-verified instantiation), 192 blocks (NT=16)
  gemm256<0, 1, 4><<<dim3(12, 16), 512, 131072, stream>>>(xb, Wqkv_t, biasq,
                                                          xqkv, 4096, 3072, 1024);
  attn_kernel<<<dim3(16, 16, 2), 256, 0, stream>>>(xqkv, madd2, ctx);
  // Wo: BN=128 variant, split-K=2 (Keff=512, NT=8), grid (8,16,2) = 256
  // blocks = full GPU; contiguous partials in dead xqkv space.
  gemm256<2, 2, 2><<<dim3(8, 16, 2), 512, 98304, stream>>>(ctx, Wo_t, nullptr,
                                                           wp, 4096, 1024, 1024);
  add_ln2p<0, 1><<<4096, 256, 0, stream>>>(x, wp, wp + 4194304, bo,
                                           ln1g, ln1b, hbuf);
  // FF1: BN=256 template with fused relu, 256 blocks (NT=16)
  gemm256<1, 1, 4><<<dim3(16, 16), 512, 131072, stream>>>(hbuf, W1_t, b1, ff1,
                                                          4096, 4096, 1024);
  // FF2: BN=128 variant, split-K=2 (Keff=2048, NT=32), 256 blocks;
  // contiguous partials at [0,16M) (all weights there dead).
  gemm256<2, 2, 2><<<dim3(8, 16, 2), 512, 98304, stream>>>(ff1, W2_t, nullptr,
                                                           fp, 4096, 1024, 4096);
  add_ln2p<1, 0><<<4096, 256, 0, stream>>>(hbuf, fp, fp + 4194304, b2,
                                           ln2g, ln2b, out);
}